// Round 1
// baseline (270.451 us; speedup 1.0000x reference)
//
#include <hip/hip_runtime.h>
#include <hip/hip_bf16.h>
#include <math.h>

// Problem constants (from reference setup_inputs): B=64, Q=16, O=20, D=256,
// NUM_CAT=101, T=4096. T is re-derived on host from out_size for safety.
constexpr int B_ = 64;
constexpr int Q_ = 16;
constexpr int O_ = 20;
constexpr int D_ = 256;

// ---------------------------------------------------------------------------
// Kernel 1: belief[b,q,d] = tanh( sum_o softmax(logits[b,q,:])[o] *
//                                 emb[cat[b,o], d] )
// Grid: B*Q blocks, D threads. Tiny (1 MiB output to workspace).
// ---------------------------------------------------------------------------
__global__ __launch_bounds__(D_) void belief_kernel(
    const float* __restrict__ logits,   // [B,Q,O]
    const float* __restrict__ emb,      // [NUM_CAT, D]
    const int*   __restrict__ cats,     // [B,O]
    float*       __restrict__ belief)   // [B,Q,D] (workspace)
{
    const int bq = blockIdx.x;          // b*Q + q
    const int b  = bq >> 4;             // Q_ == 16
    const int d  = threadIdx.x;         // 0..255

    __shared__ float s_logit[O_];
    __shared__ int   s_cat[O_];
    if (d < O_) {
        s_logit[d] = logits[bq * O_ + d];
        s_cat[d]   = cats[b * O_ + d];
    }
    __syncthreads();

    // Softmax weights, computed redundantly per thread (20 elems, broadcast
    // reads from LDS are conflict-free).
    float m = -INFINITY;
    #pragma unroll
    for (int o = 0; o < O_; ++o) m = fmaxf(m, s_logit[o]);
    float w[O_];
    float sum = 0.f;
    #pragma unroll
    for (int o = 0; o < O_; ++o) { w[o] = expf(s_logit[o] - m); sum += w[o]; }
    const float inv = 1.f / sum;

    float acc = 0.f;
    #pragma unroll
    for (int o = 0; o < O_; ++o)
        acc = fmaf(w[o] * inv, emb[s_cat[o] * D_ + d], acc);

    belief[bq * D_ + d] = tanhf(acc);
}

// ---------------------------------------------------------------------------
// Kernel 2: expansion. For each (b,t):
//   qi = #{ j in 1..Q-1 : (j <= nq[b]-1 ? cum[b,j]-1 : +inf) <= t }
//   out[b,t,:] = (qi < nq[b]-1) ? belief[b, qi, :] : 0
// Grid: (T/ROWS, B) blocks of 256 threads. Each block stages belief[b]
// (16 KB) into LDS, then streams ROWS rows of 1 KiB each with float4 stores.
// Thread layout per iteration: 4 rows x 64 lanes x float4 = 4 KiB.
// ---------------------------------------------------------------------------
constexpr int ROWS_ = 256;   // t-rows per block

__global__ __launch_bounds__(256) void expand_kernel(
    const float* __restrict__ belief,   // [B,Q,D]
    const int*   __restrict__ cum,      // [B,Q]
    const int*   __restrict__ nq_arr,   // [B]
    float*       __restrict__ out,      // [B,T,D]
    int T)
{
    const int b   = blockIdx.y;
    const int t0  = blockIdx.x * ROWS_;
    const int tid = threadIdx.x;

    __shared__ float s_belief[Q_ * D_];   // 16 KB

    // Stage belief[b] : 4096 floats = 1024 float4, 256 threads x 4.
    {
        const float4* src = (const float4*)(belief + (size_t)b * Q_ * D_);
        float4*       dst = (float4*)s_belief;
        #pragma unroll
        for (int i = 0; i < (Q_ * D_ / 4) / 256; ++i)
            dst[tid + i * 256] = src[tid + i * 256];
    }

    const int nq = nq_arr[b];
    int bnd[Q_ - 1];
    #pragma unroll
    for (int j = 1; j < Q_; ++j)
        bnd[j - 1] = (j <= nq - 1) ? (cum[b * Q_ + j] - 1) : 0x7fffffff;

    __syncthreads();

    const int col  = (tid & 63) * 4;    // float4 column offset within row
    const int rsub = tid >> 6;          // 0..3: row within the 4-row group

    #pragma unroll 4
    for (int it = 0; it < ROWS_ / 4; ++it) {
        const int t = t0 + it * 4 + rsub;
        if (t >= T) break;

        int qi = 0;
        #pragma unroll
        for (int j = 0; j < Q_ - 1; ++j) qi += (t >= bnd[j]) ? 1 : 0;

        float4 v = make_float4(0.f, 0.f, 0.f, 0.f);
        if (qi < nq - 1) {
            const int qc = qi < (Q_ - 1) ? qi : (Q_ - 1);
            v = *(const float4*)(s_belief + qc * D_ + col);
        }
        *(float4*)(out + ((size_t)b * T + t) * (size_t)D_ + col) = v;
    }
}

extern "C" void kernel_launch(void* const* d_in, const int* in_sizes, int n_in,
                              void* d_out, int out_size, void* d_ws, size_t ws_size,
                              hipStream_t stream)
{
    const float* logits = (const float*)d_in[0];   // [B,Q,O] fp32
    const float* emb    = (const float*)d_in[1];   // [101,D] fp32
    const int*   cats   = (const int*)d_in[2];     // [B,O] int32
    const int*   cum    = (const int*)d_in[3];     // [B,Q] int32
    const int*   nq     = (const int*)d_in[4];     // [B] int32
    // d_in[5] = max_dln scalar; T derived from out_size instead.

    float* out    = (float*)d_out;
    float* belief = (float*)d_ws;                  // B*Q*D floats = 1 MiB

    const int T = out_size / (B_ * D_);            // 4096

    belief_kernel<<<B_ * Q_, D_, 0, stream>>>(logits, emb, cats, belief);

    dim3 grid((T + ROWS_ - 1) / ROWS_, B_);
    expand_kernel<<<grid, 256, 0, stream>>>(belief, cum, nq, out, T);
}